// Round 4
// baseline (147.431 us; speedup 1.0000x reference)
//
#include <hip/hip_runtime.h>
#include <hip/hip_bf16.h>
#include <math.h>

#define ALPHA 0.25f
#define EPS 1e-8f

// ---------------------------------------------------------------------------
// Kernel 1: precompute per-(bq,c) focal class cost  cc = pos_cost - neg_cost
// Only BQ*C = 57600 elements; removes all transcendentals from the 23M-pair
// main loop. Precise expf/logf (off critical path).
// ---------------------------------------------------------------------------
__global__ __launch_bounds__(256) void class_cost_kernel(
    const float* __restrict__ logits,  // [BQ*C]
    float* __restrict__ cc,            // [BQ*C]
    int n)
{
    int i = blockIdx.x * 256 + threadIdx.x;
    if (i >= n) return;
    float x = logits[i];
    float p = 1.0f / (1.0f + expf(-x));
    float om = 1.0f - p;
    float pos = ALPHA * om * om * (-logf(p + EPS));
    float neg = (1.0f - ALPHA) * p * p * (-logf(om + EPS));
    cc[i] = pos - neg;
}

// ---------------------------------------------------------------------------
// Kernel 2: pairwise cost  [BQ, T] = L1 + class - GIoU
// Thread = 4 consecutive targets (float4 store per bq row: 64 lanes x 16B =
// 1KiB/wave-store, the measured-6.3TB/s pattern). Pred-side loads are
// wave-uniform (scalar s_load path); target-side setup hoisted out of the
// 16-deep bq loop.
// ---------------------------------------------------------------------------
#define BQ_TILE 16

__global__ __launch_bounds__(256) void cost_kernel(
    const float* __restrict__ pred_bbox,  // [BQ,4] cxcywh
    const float* __restrict__ tgt_bbox,   // [T,4]  cxcywh
    const int*   __restrict__ labels,     // [T]
    const float* __restrict__ cc,         // [BQ,4]
    float* __restrict__ out,              // [BQ,T]
    int BQ, int T)
{
    int tg = blockIdx.x * 256 + threadIdx.x;   // target-group index
    int t0 = tg * 4;
    if (t0 >= T) return;
    int bq0 = blockIdx.y * BQ_TILE;

    // ---- target-side setup: 4 targets per thread ----
    float4 tb[4];
    float tx0[4], ty0[4], tx1[4], ty1[4], area2[4];
    int lab[4];
    int4 lv = reinterpret_cast<const int4*>(labels)[tg];
    lab[0] = lv.x; lab[1] = lv.y; lab[2] = lv.z; lab[3] = lv.w;
    #pragma unroll
    for (int j = 0; j < 4; ++j) {
        tb[j] = reinterpret_cast<const float4*>(tgt_bbox)[t0 + j];
        tx0[j] = tb[j].x - 0.5f * tb[j].z;
        ty0[j] = tb[j].y - 0.5f * tb[j].w;
        tx1[j] = tb[j].x + 0.5f * tb[j].z;
        ty1[j] = tb[j].y + 0.5f * tb[j].w;
        area2[j] = tb[j].z * tb[j].w;
    }

    #pragma unroll
    for (int i = 0; i < BQ_TILE; ++i) {
        int bq = bq0 + i;
        if (bq >= BQ) break;
        // wave-uniform loads -> scalar path
        float4 pb = reinterpret_cast<const float4*>(pred_bbox)[bq];
        float4 cv = reinterpret_cast<const float4*>(cc)[bq];

        float px0 = pb.x - 0.5f * pb.z;
        float py0 = pb.y - 0.5f * pb.w;
        float px1 = pb.x + 0.5f * pb.z;
        float py1 = pb.y + 0.5f * pb.w;
        float area1 = pb.z * pb.w;

        float r[4];
        #pragma unroll
        for (int j = 0; j < 4; ++j) {
            // class cost: select among 4 wave-uniform values by per-lane label
            float cls = (lab[j] == 0) ? cv.x : (lab[j] == 1) ? cv.y
                       : (lab[j] == 2) ? cv.z : cv.w;

            // L1 on cxcywh
            float l1 = fabsf(pb.x - tb[j].x) + fabsf(pb.y - tb[j].y)
                     + fabsf(pb.z - tb[j].z) + fabsf(pb.w - tb[j].w);

            // GIoU on corners
            float iw = fminf(px1, tx1[j]) - fmaxf(px0, tx0[j]); iw = fmaxf(iw, 0.0f);
            float ih = fminf(py1, ty1[j]) - fmaxf(py0, ty0[j]); ih = fmaxf(ih, 0.0f);
            float inter = iw * ih;
            float uni = area1 + area2[j] - inter;
            float iou = inter / (uni + EPS);
            float ew = fmaxf(px1, tx1[j]) - fminf(px0, tx0[j]);
            float eh = fmaxf(py1, ty1[j]) - fminf(py0, ty0[j]);
            float area_e = ew * eh;
            float giou = iou - (area_e - uni) / (area_e + EPS);

            r[j] = l1 + cls - giou;
        }
        float4 o = make_float4(r[0], r[1], r[2], r[3]);
        reinterpret_cast<float4*>(&out[(size_t)bq * T + t0])[0] = o;
    }
}

extern "C" void kernel_launch(void* const* d_in, const int* in_sizes, int n_in,
                              void* d_out, int out_size, void* d_ws, size_t ws_size,
                              hipStream_t stream) {
    const float* logits    = (const float*)d_in[0];  // [B,Q,C]
    const float* pred_bbox = (const float*)d_in[1];  // [B,Q,4]
    const float* tgt_bbox  = (const float*)d_in[2];  // [T,4]
    const int*   labels    = (const int*)d_in[3];    // [T]

    int BQ = in_sizes[1] / 4;          // B*Q = 14400
    int T  = in_sizes[3];              // 1600

    float* cc = (float*)d_ws;          // [BQ, C] scratch

    int n_cc = in_sizes[0];            // BQ*C
    class_cost_kernel<<<(n_cc + 255) / 256, 256, 0, stream>>>(logits, cc, n_cc);

    int tgroups = T / 4;               // 400 (T is a multiple of 4)
    dim3 grid((tgroups + 255) / 256, (BQ + BQ_TILE - 1) / BQ_TILE);
    cost_kernel<<<grid, 256, 0, stream>>>(pred_bbox, tgt_bbox, labels, cc,
                                          (float*)d_out, BQ, T);
}

// Round 5
// 124.660 us; speedup vs baseline: 1.1827x; 1.1827x over previous
//
#include <hip/hip_runtime.h>
#include <hip/hip_bf16.h>
#include <math.h>

#define ALPHA 0.25f
#define EPS 1e-8f

// ---------------------------------------------------------------------------
// Kernel 1: per-(bq,c) focal class cost, with the GIoU-identity constant +1
// baked in:  cc' = pos - neg + 1
// 57600 elements -> ~2-3 us; keeps all transcendentals off the 23M-pair loop.
// ---------------------------------------------------------------------------
__global__ __launch_bounds__(256) void class_cost_kernel(
    const float* __restrict__ logits,  // [BQ*C]
    float* __restrict__ cc,            // [BQ*C]
    int n)
{
    int i = blockIdx.x * 256 + threadIdx.x;
    if (i >= n) return;
    float x = logits[i];
    float p = 1.0f / (1.0f + expf(-x));
    float om = 1.0f - p;
    float pos = ALPHA * om * om * (-logf(p + EPS));
    float neg = (1.0f - ALPHA) * p * p * (-logf(om + EPS));
    cc[i] = pos - neg + 1.0f;
}

// ---------------------------------------------------------------------------
// Kernel 2: pairwise cost [BQ, T].
// Exact algebra:  giou = inter/u - 1 + u/ae   (u = uni+EPS, ae = area_e+EPS)
//   => cost = l1 + (cls+1) - (inter*ae + u^2) / (u*ae)    -- ONE division
// and  ew = (pw+tw) - iw_raw  via min+max=sum identity.
// Single v_rcp_f32 per pair instead of two precise-div sequences.
// ---------------------------------------------------------------------------
#define BQ_TILE 16

__global__ __launch_bounds__(256) void cost_kernel(
    const float* __restrict__ pred_bbox,  // [BQ,4] cxcywh
    const float* __restrict__ tgt_bbox,   // [T,4]  cxcywh
    const int*   __restrict__ labels,     // [T]
    const float* __restrict__ cc,         // [BQ,4] (class cost + 1)
    float* __restrict__ out,              // [BQ,T]
    int BQ, int T)
{
    int tg = blockIdx.x * 256 + threadIdx.x;   // target-group index
    int t0 = tg * 4;
    if (t0 >= T) return;
    int bq0 = blockIdx.y * BQ_TILE;

    // ---- target-side setup: 4 targets per thread (hoisted) ----
    float4 tb[4];
    float tx0[4], ty0[4], tx1[4], ty1[4], a2e[4];
    int lab[4];
    int4 lv = reinterpret_cast<const int4*>(labels)[tg];
    lab[0] = lv.x; lab[1] = lv.y; lab[2] = lv.z; lab[3] = lv.w;
    #pragma unroll
    for (int j = 0; j < 4; ++j) {
        tb[j] = reinterpret_cast<const float4*>(tgt_bbox)[t0 + j];
        tx0[j] = tb[j].x - 0.5f * tb[j].z;
        ty0[j] = tb[j].y - 0.5f * tb[j].w;
        tx1[j] = tb[j].x + 0.5f * tb[j].z;
        ty1[j] = tb[j].y + 0.5f * tb[j].w;
        a2e[j] = tb[j].z * tb[j].w + EPS;   // area2 + EPS pre-folded
    }

    #pragma unroll
    for (int i = 0; i < BQ_TILE; ++i) {
        int bq = bq0 + i;
        if (bq >= BQ) break;
        // wave-uniform loads -> scalar path
        float4 pb = reinterpret_cast<const float4*>(pred_bbox)[bq];
        float4 cv = reinterpret_cast<const float4*>(cc)[bq];

        float px0 = pb.x - 0.5f * pb.z;
        float py0 = pb.y - 0.5f * pb.w;
        float px1 = pb.x + 0.5f * pb.z;
        float py1 = pb.y + 0.5f * pb.w;
        float area1 = pb.z * pb.w;

        float r[4];
        #pragma unroll
        for (int j = 0; j < 4; ++j) {
            // class cost (+1 baked in): 3 cndmask, compares hoisted by compiler
            float cls = (lab[j] == 0) ? cv.x : (lab[j] == 1) ? cv.y
                       : (lab[j] == 2) ? cv.z : cv.w;

            // L1 on cxcywh (abs folds into VOP3 modifiers)
            float l1 = (fabsf(pb.x - tb[j].x) + fabsf(pb.y - tb[j].y))
                     + (fabsf(pb.z - tb[j].z) + fabsf(pb.w - tb[j].w));

            // intersection (raw widths kept for the enclosing-box identity)
            float iwr = fminf(px1, tx1[j]) - fmaxf(px0, tx0[j]);
            float ihr = fminf(py1, ty1[j]) - fmaxf(py0, ty0[j]);
            float iw = fmaxf(iwr, 0.0f);
            float ih = fmaxf(ihr, 0.0f);
            float inter = iw * ih;

            // enclosing box via min+max=sum identity
            float ew = (pb.z + tb[j].z) - iwr;
            float eh = (pb.w + tb[j].w) - ihr;
            float ae = fmaf(ew, eh, EPS);            // area_e + EPS

            float u = (area1 + a2e[j]) - inter;      // union + EPS

            // inter/u + u/ae == (inter*ae + u*u) / (u*ae) -- one division
            float num = fmaf(inter, ae, u * u);
            float den = u * ae;
            float q = num * __builtin_amdgcn_rcpf(den);

            r[j] = (l1 + cls) - q;
        }
        float4 o = make_float4(r[0], r[1], r[2], r[3]);
        reinterpret_cast<float4*>(&out[(size_t)bq * T + t0])[0] = o;
    }
}

extern "C" void kernel_launch(void* const* d_in, const int* in_sizes, int n_in,
                              void* d_out, int out_size, void* d_ws, size_t ws_size,
                              hipStream_t stream) {
    const float* logits    = (const float*)d_in[0];  // [B,Q,C]
    const float* pred_bbox = (const float*)d_in[1];  // [B,Q,4]
    const float* tgt_bbox  = (const float*)d_in[2];  // [T,4]
    const int*   labels    = (const int*)d_in[3];    // [T]

    int BQ = in_sizes[1] / 4;          // B*Q = 14400
    int T  = in_sizes[3];              // 1600

    float* cc = (float*)d_ws;          // [BQ, C] scratch

    int n_cc = in_sizes[0];            // BQ*C
    class_cost_kernel<<<(n_cc + 255) / 256, 256, 0, stream>>>(logits, cc, n_cc);

    int tgroups = T / 4;               // 400
    dim3 grid((tgroups + 255) / 256, (BQ + BQ_TILE - 1) / BQ_TILE);
    cost_kernel<<<grid, 256, 0, stream>>>(pred_bbox, tgt_bbox, labels, cc,
                                          (float*)d_out, BQ, T);
}

// Round 11
// 116.316 us; speedup vs baseline: 1.2675x; 1.0717x over previous
//
#include <hip/hip_runtime.h>
#include <hip/hip_bf16.h>
#include <math.h>

#define ALPHA 0.25f
#define EPS 1e-8f
#define BQ_TILE 16

// ---------------------------------------------------------------------------
// Kernel 1: prep tables.
//  (a) per-(bq,c) focal class cost with GIoU-identity "+1" baked in
//  (b) per-bq pred corners {px0,py0,px1,py1}
// Removes all transcendentals AND the uniform corner math from the main loop.
// ---------------------------------------------------------------------------
__global__ __launch_bounds__(256) void prep_kernel(
    const float* __restrict__ logits,     // [BQ*C]
    const float* __restrict__ pred_bbox,  // [BQ,4]
    float* __restrict__ cc,               // [BQ*C] out: class cost + 1
    float4* __restrict__ pcorn,           // [BQ]   out: corners
    int n_cc, int BQ)
{
    int i = blockIdx.x * 256 + threadIdx.x;
    if (i < n_cc) {
        float x = logits[i];
        float p = 1.0f / (1.0f + expf(-x));
        float om = 1.0f - p;
        float pos = ALPHA * om * om * (-logf(p + EPS));
        float neg = (1.0f - ALPHA) * p * p * (-logf(om + EPS));
        cc[i] = pos - neg + 1.0f;
    }
    if (i < BQ) {
        float4 pb = reinterpret_cast<const float4*>(pred_bbox)[i];
        float4 c;
        c.x = pb.x - 0.5f * pb.z;
        c.y = pb.y - 0.5f * pb.w;
        c.z = pb.x + 0.5f * pb.z;
        c.w = pb.y + 0.5f * pb.w;
        pcorn[i] = c;
    }
}

// ---------------------------------------------------------------------------
// Kernel 2: pairwise cost [BQ, T].
//   cost = l1 + (cls+1) - (inter*ae + u^2)/(u*ae)   (exact; EPS terms cancel)
// Wave-unit decomposition: unit = (t-chunk of 64 tgroups) x (16-bq tile).
// Per-wave LDS slice for class-cost gather (ds_read, 0 VALU, no barrier).
// ---------------------------------------------------------------------------
__global__ __launch_bounds__(256) void cost_kernel(
    const float* __restrict__ pred_bbox,  // [BQ,4] cxcywh
    const float4* __restrict__ pcorn,     // [BQ]   corners
    const float* __restrict__ tgt_bbox,   // [T,4]  cxcywh
    const int*   __restrict__ labels,     // [T]
    const float* __restrict__ cc,         // [BQ,4] class cost + 1
    float* __restrict__ out,              // [BQ,T]
    int BQ, int T, int nTC, int nWU)
{
    __shared__ float s_cc[4 * BQ_TILE * 4];   // [wave][16 bq][4 classes]

    int wslot = threadIdx.x >> 6;
    int lane  = threadIdx.x & 63;
    int wu = blockIdx.x * 4 + wslot;
    if (wu >= nWU) return;
    int tc  = wu % nTC;          // t-chunk (64 tgroups each)
    int bqt = wu / nTC;          // bq tile (16 rows)
    int bq0 = bqt * BQ_TILE;

    // stage this wave's 64-float class-cost slice (same-wave use -> no barrier)
    s_cc[wslot * 64 + lane] = cc[bq0 * 4 + lane];

    int tg = tc * 64 + lane;     // target-group index (4 targets each)
    int TG = T >> 2;
    if (tg >= TG) return;
    int t0 = tg * 4;

    // ---- target-side setup: 4 targets per thread (hoisted) ----
    float4 tb[4];
    float tx0[4], ty0[4], tx1[4], ty1[4], a2e[4];
    int lidx[4];
    int4 lv = reinterpret_cast<const int4*>(labels)[tg];
    int lbl[4] = {lv.x, lv.y, lv.z, lv.w};
    #pragma unroll
    for (int j = 0; j < 4; ++j) {
        tb[j] = reinterpret_cast<const float4*>(tgt_bbox)[t0 + j];
        tx0[j] = tb[j].x - 0.5f * tb[j].z;
        ty0[j] = tb[j].y - 0.5f * tb[j].w;
        tx1[j] = tb[j].x + 0.5f * tb[j].z;
        ty1[j] = tb[j].y + 0.5f * tb[j].w;
        a2e[j] = tb[j].z * tb[j].w + EPS;        // area2 + EPS pre-folded
        lidx[j] = wslot * 64 + lbl[j];           // LDS gather base (bq adds i*4)
    }

    #pragma unroll
    for (int i = 0; i < BQ_TILE; ++i) {          // no break: BQ % 16 == 0
        int bq = bq0 + i;
        // wave-uniform loads -> scalar path, pipelined across the full unroll
        float4 pb = reinterpret_cast<const float4*>(pred_bbox)[bq];
        float4 pc = pcorn[bq];
        float area1 = pb.z * pb.w;

        float r[4];
        #pragma unroll
        for (int j = 0; j < 4; ++j) {
            // class cost (+1): LDS gather, immediate offset i*16B, 0 VALU
            float cls = s_cc[lidx[j] + i * 4];

            // L1 on cxcywh
            float l1 = (fabsf(pb.x - tb[j].x) + fabsf(pb.y - tb[j].y))
                     + (fabsf(pb.z - tb[j].z) + fabsf(pb.w - tb[j].w));

            // intersection (raw widths kept for enclosing-box identity)
            float iwr = fminf(pc.z, tx1[j]) - fmaxf(pc.x, tx0[j]);
            float ihr = fminf(pc.w, ty1[j]) - fmaxf(pc.y, ty0[j]);
            float iw = fmaxf(iwr, 0.0f);
            float ih = fmaxf(ihr, 0.0f);
            float inter = iw * ih;

            // enclosing box via min+max=sum identity
            float ew = (pb.z + tb[j].z) - iwr;
            float eh = (pb.w + tb[j].w) - ihr;
            float ae = fmaf(ew, eh, EPS);        // area_e + EPS

            float u = (area1 + a2e[j]) - inter;  // union + EPS

            // inter/u + u/ae == (inter*ae + u*u)/(u*ae) -- one rcp
            float num = fmaf(inter, ae, u * u);
            float q = num * __builtin_amdgcn_rcpf(u * ae);

            r[j] = (l1 + cls) - q;
        }
        *reinterpret_cast<float4*>(&out[(size_t)bq * T + t0]) =
            make_float4(r[0], r[1], r[2], r[3]);
    }
}

extern "C" void kernel_launch(void* const* d_in, const int* in_sizes, int n_in,
                              void* d_out, int out_size, void* d_ws, size_t ws_size,
                              hipStream_t stream) {
    const float* logits    = (const float*)d_in[0];  // [B,Q,C]
    const float* pred_bbox = (const float*)d_in[1];  // [B,Q,4]
    const float* tgt_bbox  = (const float*)d_in[2];  // [T,4]
    const int*   labels    = (const int*)d_in[3];    // [T]

    int BQ = in_sizes[1] / 4;          // 14400
    int T  = in_sizes[3];              // 1600

    float*  cc    = (float*)d_ws;                    // [BQ,4]
    float4* pcorn = (float4*)((char*)d_ws + (size_t)in_sizes[0] * sizeof(float));

    int n_cc = in_sizes[0];            // BQ*C
    int nprep = n_cc > BQ ? n_cc : BQ;
    prep_kernel<<<(nprep + 255) / 256, 256, 0, stream>>>(
        logits, pred_bbox, cc, pcorn, n_cc, BQ);

    int TG  = T / 4;                       // 400 target-groups
    int nTC = (TG + 63) / 64;              // 7 t-chunks
    int nBT = BQ / BQ_TILE;                // 900 bq tiles
    int nWU = nTC * nBT;                   // 6300 wave units
    int blocks = (nWU + 3) / 4;            // 4 waves per block
    cost_kernel<<<blocks, 256, 0, stream>>>(pred_bbox, pcorn, tgt_bbox, labels,
                                            cc, (float*)d_out, BQ, T, nTC, nWU);
}